// Round 1
// baseline (451.953 us; speedup 1.0000x reference)
//
#include <hip/hip_runtime.h>
#include <math.h>

#define BLOCK   384
#define I_CAPS  1152
#define O_CAPS  32
#define D_DIM   16
#define ROWS    3          // I_CAPS / BLOCK
#define K_SEL   922        // ceil(0.8 * 1152)
#define NWAVES  6          // BLOCK / 64

__device__ __forceinline__ float wave_reduce_sum(float v) {
    #pragma unroll
    for (int off = 32; off > 0; off >>= 1) v += __shfl_down(v, off);
    return v;
}

__global__ __launch_bounds__(BLOCK, 3)
void subset_routing_kernel(const float* __restrict__ u, float* __restrict__ out) {
    __shared__ float red[NWAVES][17];
    __shared__ float sh_v[D_DIM];
    __shared__ int   hist[256];
    __shared__ unsigned sh_prefix;
    __shared__ int   sh_k;

    const int t    = threadIdx.x;
    const int lane = t & 63;
    const int wave = t >> 6;

    // block -> (b,o): pair (b,2j) and (b,2j+1) onto the same XCD (mod-8)
    int X = blockIdx.x;
    int r = X & 7;
    int m = (X >> 3) & 1;
    int q = X >> 4;
    int p = q * 8 + r;            // pair id in [0,2048)
    int b = p >> 4;               // [0,128)
    int o = ((p & 15) << 1) | m;  // [0,32)

    const float4* base =
        (const float4*)u + (((size_t)b * I_CAPS) * O_CAPS + (size_t)o) * (D_DIM / 4);

    // ---- load 3 rows (each 16 floats = one 64B line) into registers ----
    float uu[ROWS][D_DIM];
    float nn[ROWS];
    #pragma unroll
    for (int rr = 0; rr < ROWS; ++rr) {
        int i = t + rr * BLOCK;
        const float4* rowp = base + (size_t)i * (O_CAPS * (D_DIM / 4));
        float4 a0 = rowp[0], a1 = rowp[1], a2 = rowp[2], a3 = rowp[3];
        uu[rr][ 0]=a0.x; uu[rr][ 1]=a0.y; uu[rr][ 2]=a0.z; uu[rr][ 3]=a0.w;
        uu[rr][ 4]=a1.x; uu[rr][ 5]=a1.y; uu[rr][ 6]=a1.z; uu[rr][ 7]=a1.w;
        uu[rr][ 8]=a2.x; uu[rr][ 9]=a2.y; uu[rr][10]=a2.z; uu[rr][11]=a2.w;
        uu[rr][12]=a3.x; uu[rr][13]=a3.y; uu[rr][14]=a3.z; uu[rr][15]=a3.w;
    }

    // ---- per-row norms + partial weighted sums ----
    float num_acc[D_DIM];
    #pragma unroll
    for (int d = 0; d < D_DIM; ++d) num_acc[d] = 0.f;
    float den_acc = 0.f;
    #pragma unroll
    for (int rr = 0; rr < ROWS; ++rr) {
        float s = 0.f;
        #pragma unroll
        for (int d = 0; d < D_DIM; ++d) s += uu[rr][d] * uu[rr][d];
        nn[rr] = sqrtf(s);
        den_acc += nn[rr];
        #pragma unroll
        for (int d = 0; d < D_DIM; ++d) num_acc[d] += uu[rr][d] * nn[rr];
    }

    // ---- block reduction: v = num/den ----
    #pragma unroll
    for (int d = 0; d < D_DIM; ++d) {
        float s = wave_reduce_sum(num_acc[d]);
        if (lane == 0) red[wave][d] = s;
    }
    {
        float s = wave_reduce_sum(den_acc);
        if (lane == 0) red[wave][16] = s;
    }
    __syncthreads();
    if (t < D_DIM) {
        float tot = 0.f, dtot = 0.f;
        #pragma unroll
        for (int w = 0; w < NWAVES; ++w) { tot += red[w][t]; dtot += red[w][16]; }
        sh_v[t] = tot / dtot;
    }
    __syncthreads();

    float vv[D_DIM];
    #pragma unroll
    for (int d = 0; d < D_DIM; ++d) vv[d] = sh_v[d];

    // ---- losses -> order-preserving uint keys (kept in registers) ----
    unsigned key[ROWS];
    #pragma unroll
    for (int rr = 0; rr < ROWS; ++rr) {
        float loss = 0.f;
        #pragma unroll
        for (int d = 0; d < D_DIM; ++d) loss += vv[d] * uu[rr][d];
        loss = -loss;
        unsigned bits = __float_as_uint(loss);
        unsigned msk  = ((unsigned)((int)bits >> 31)) | 0x80000000u;
        key[rr] = bits ^ msk;
    }

    // ---- exact k-th smallest via 4-round MSD radix select ----
    unsigned prefix = 0u;
    int kk = K_SEL;
    #pragma unroll
    for (int shift = 24; shift >= 0; shift -= 8) {
        if (t < 256) hist[t] = 0;
        __syncthreads();
        unsigned maskAbove = (shift == 24) ? 0u : (0xFFFFFFFFu << (shift + 8));
        #pragma unroll
        for (int rr = 0; rr < ROWS; ++rr) {
            unsigned k = key[rr];
            if ((k & maskAbove) == prefix)
                atomicAdd(&hist[(k >> shift) & 255u], 1);
        }
        __syncthreads();
        if (wave == 0) {
            int c0 = hist[lane*4+0], c1 = hist[lane*4+1],
                c2 = hist[lane*4+2], c3 = hist[lane*4+3];
            int s = c0 + c1 + c2 + c3;
            int cum = s;
            #pragma unroll
            for (int off = 1; off < 64; off <<= 1) {
                int vsh = __shfl_up(cum, off);
                if (lane >= off) cum += vsh;
            }
            int cumprev = cum - s;
            bool has = (cumprev < kk) && (cum >= kk);
            unsigned long long ball = __ballot(has);
            int win = __ffsll(ball) - 1;
            if (lane == win) {
                int kr = kk - cumprev;
                int digit = 0;
                if (kr > c0) { kr -= c0; digit = 1;
                    if (kr > c1) { kr -= c1; digit = 2;
                        if (kr > c2) { kr -= c2; digit = 3; } } }
                sh_prefix = prefix | ((unsigned)(lane*4 + digit) << shift);
                sh_k = kr;
            }
        }
        __syncthreads();
        prefix = sh_prefix;
        kk = sh_k;
    }
    // prefix == exact k-th smallest key; choose = (key <= prefix)

    // ---- masked weighted average (u, n still in registers) ----
    float num2[D_DIM];
    #pragma unroll
    for (int d = 0; d < D_DIM; ++d) num2[d] = 0.f;
    float den2 = 0.f;
    #pragma unroll
    for (int rr = 0; rr < ROWS; ++rr) {
        float msk = (key[rr] <= prefix) ? 1.0f : 0.0f;
        float w = nn[rr] * msk;
        den2 += w;
        #pragma unroll
        for (int d = 0; d < D_DIM; ++d) num2[d] += uu[rr][d] * w;
    }

    #pragma unroll
    for (int d = 0; d < D_DIM; ++d) {
        float s = wave_reduce_sum(num2[d]);
        if (lane == 0) red[wave][d] = s;
    }
    {
        float s = wave_reduce_sum(den2);
        if (lane == 0) red[wave][16] = s;
    }
    __syncthreads();
    if (t < D_DIM) {
        float tot = 0.f, dtot = 0.f;
        #pragma unroll
        for (int w = 0; w < NWAVES; ++w) { tot += red[w][t]; dtot += red[w][16]; }
        out[(((size_t)b * O_CAPS) + o) * D_DIM + t] = tot / dtot;
    }
}

extern "C" void kernel_launch(void* const* d_in, const int* in_sizes, int n_in,
                              void* d_out, int out_size, void* d_ws, size_t ws_size,
                              hipStream_t stream) {
    const float* u = (const float*)d_in[0];
    float* out = (float*)d_out;
    const int B = 128;
    subset_routing_kernel<<<dim3(B * O_CAPS), dim3(BLOCK), 0, stream>>>(u, out);
}